// Round 11
// baseline (104.166 us; speedup 1.0000x reference)
//
#include <hip/hip_runtime.h>

// R11 DIAGNOSTIC ROUND. Three >43us dispatches so each ranks above the ~40us
// harness fills in rocprof top-5:
//  1) affinity_diag_main: R2 kernel x2 passes (correct output, stored twice).
//  2) probe_stream: perfectly-coalesced pure read of input, 6 passes (384 MB).
//  3) probe_2row:  R4's center+south row-pair read pattern, 3 passes (384 MB).
// z (runtime 0) offsets each pass's base pointer to defeat cross-pass CSE.

#define AF_B 4
#define AF_C 32
#define AF_H 256
#define AF_W 512
#define AF_EPS 1e-12f
#define AF_PLANE ((size_t)AF_H * AF_W)

// ---------------------------------------------------------------- main x2
__global__ __launch_bounds__(256) void affinity_diag_main(const float* f,
                                                          float* out,
                                                          size_t z) {
    const int cpx = gridDim.x >> 3;
    const int bid = ((int)blockIdx.x & 7) * cpx + ((int)blockIdx.x >> 3);
    const int wband = bid & 3;
    const int hband = (bid >> 2) & 31;
    const int b = bid >> 7;

    const int g = (int)threadIdx.x & 31;
    const int r = (int)threadIdx.x >> 5;
    const int w0 = (wband << 7) + (g << 2);
    const int h = (hband << 3) + r;

    const bool vS = (h + 1) < AF_H;
    const bool vR = (w0 + 4) < AF_W;
    const bool vL = w0 > 0;
    const float mS = vS ? 1.0f : 0.0f;
    const float mR = vR ? 1.0f : 0.0f;
    const float mRS = mR * mS;
    const float mLS = (vL ? 1.0f : 0.0f) * mS;
    const int offR = vR ? 4 : 0;
    const int offL = vL ? -1 : 0;

    for (int pass = 0; pass < 2; ++pass) {
        const float* pc = f + pass * z + (size_t)b * AF_C * AF_PLANE
                        + (size_t)h * AF_W + w0;
        const float* ps = pc + (vS ? AF_W : 0);

        float ssq0=0,ssq1=0,ssq2=0,ssq3=0, ssqR=0;
        float nsq0=0,nsq1=0,nsq2=0,nsq3=0, nsqL=0,nsqR=0;
        float dE0=0,dE1=0,dE2=0,dE3=0;
        float dS0=0,dS1=0,dS2=0,dS3=0;
        float dSE0=0,dSE1=0,dSE2=0,dSE3=0;
        float dSW0=0,dSW1=0,dSW2=0,dSW3=0;

#pragma unroll
        for (int c = 0; c < AF_C; ++c) {
            const float4 cc = *(const float4*)pc;
            const float ccR = pc[offR] * mR;
            float4 cs = *(const float4*)ps;
            const float csR = ps[offR] * mRS;
            const float csL = ps[offL] * mLS;
            cs.x *= mS; cs.y *= mS; cs.z *= mS; cs.w *= mS;
            pc += AF_PLANE; ps += AF_PLANE;

            ssq0 += cc.x*cc.x; ssq1 += cc.y*cc.y; ssq2 += cc.z*cc.z; ssq3 += cc.w*cc.w;
            ssqR += ccR*ccR;
            nsq0 += cs.x*cs.x; nsq1 += cs.y*cs.y; nsq2 += cs.z*cs.z; nsq3 += cs.w*cs.w;
            nsqL += csL*csL;   nsqR += csR*csR;
            dE0 += cc.x*cc.y;  dE1 += cc.y*cc.z;  dE2 += cc.z*cc.w;  dE3 += cc.w*ccR;
            dS0 += cc.x*cs.x;  dS1 += cc.y*cs.y;  dS2 += cc.z*cs.z;  dS3 += cc.w*cs.w;
            dSE0 += cc.x*cs.y; dSE1 += cc.y*cs.z; dSE2 += cc.z*cs.w; dSE3 += cc.w*csR;
            dSW0 += cc.x*csL;  dSW1 += cc.y*cs.x; dSW2 += cc.z*cs.y; dSW3 += cc.w*cs.z;
        }

        const float ic0 = 1.0f / fmaxf(sqrtf(ssq0), AF_EPS);
        const float ic1 = 1.0f / fmaxf(sqrtf(ssq1), AF_EPS);
        const float ic2 = 1.0f / fmaxf(sqrtf(ssq2), AF_EPS);
        const float ic3 = 1.0f / fmaxf(sqrtf(ssq3), AF_EPS);
        const float icR = 1.0f / fmaxf(sqrtf(ssqR), AF_EPS);
        const float is0 = 1.0f / fmaxf(sqrtf(nsq0), AF_EPS);
        const float is1 = 1.0f / fmaxf(sqrtf(nsq1), AF_EPS);
        const float is2 = 1.0f / fmaxf(sqrtf(nsq2), AF_EPS);
        const float is3 = 1.0f / fmaxf(sqrtf(nsq3), AF_EPS);
        const float isL = 1.0f / fmaxf(sqrtf(nsqL), AF_EPS);
        const float isR = 1.0f / fmaxf(sqrtf(nsqR), AF_EPS);

        const float E0 = fmaxf(dE0*ic0*ic1, 0.0f);
        const float E1 = fmaxf(dE1*ic1*ic2, 0.0f);
        const float E2 = fmaxf(dE2*ic2*ic3, 0.0f);
        const float E3 = fmaxf(dE3*ic3*icR, 0.0f);
        const float S0 = fmaxf(dS0*ic0*is0, 0.0f);
        const float S1 = fmaxf(dS1*ic1*is1, 0.0f);
        const float S2 = fmaxf(dS2*ic2*is2, 0.0f);
        const float S3 = fmaxf(dS3*ic3*is3, 0.0f);
        const float SE0 = fmaxf(dSE0*ic0*is1, 0.0f);
        const float SE1 = fmaxf(dSE1*ic1*is2, 0.0f);
        const float SE2 = fmaxf(dSE2*ic2*is3, 0.0f);
        const float SE3 = fmaxf(dSE3*ic3*isR, 0.0f);
        const float SW0 = fmaxf(dSW0*ic0*isL, 0.0f);
        const float SW1 = fmaxf(dSW1*ic1*is0, 0.0f);
        const float SW2 = fmaxf(dSW2*ic2*is1, 0.0f);
        const float SW3 = fmaxf(dSW3*ic3*is2, 0.0f);

        float* ob = out + (size_t)b * 8 * AF_PLANE + (size_t)h * AF_W + w0;

        *(float4*)(ob + 4*AF_PLANE) = make_float4(E0,E1,E2,E3);
        *(float4*)(ob + 6*AF_PLANE) = make_float4(S0,S1,S2,S3);
        *(float4*)(ob + 7*AF_PLANE) = make_float4(SE0,SE1,SE2,SE3);
        *(float4*)(ob + 5*AF_PLANE) = make_float4(SW0,SW1,SW2,SW3);

        float* o3 = ob + 3*AF_PLANE;
        o3[1] = E0; o3[2] = E1; o3[3] = E2;
        if (vR) o3[4] = E3;
        if (!vL) o3[0] = 0.0f;

        if (vS) {
            float* on = ob + AF_W;
            *(float4*)(on + 1*AF_PLANE) = make_float4(S0,S1,S2,S3);
            float* o0 = on;
            o0[1] = SE0; o0[2] = SE1; o0[3] = SE2;
            if (vR) o0[4] = SE3;
            if (!vL) o0[0] = 0.0f;
            float* o2 = on + 2*AF_PLANE;
            if (vL) o2[-1] = SW0;
            o2[0] = SW1; o2[1] = SW2; o2[2] = SW3;
            if (!vR) o2[3] = 0.0f;
        }

        if (h == 0) {
            float* oz = out + (size_t)b * 8 * AF_PLANE + w0;
            const float4 z4 = make_float4(0.0f, 0.0f, 0.0f, 0.0f);
            *(float4*)(oz + 0*AF_PLANE) = z4;
            *(float4*)(oz + 1*AF_PLANE) = z4;
            *(float4*)(oz + 2*AF_PLANE) = z4;
        }
    }
}

// ------------------------------------------------- probe 1: pure stream read
// 2048 blocks x 256 thr; 6 passes x 64 MB perfectly-coalesced float4 reads.
__global__ __launch_bounds__(256) void probe_stream(const float* f,
                                                    float* ws, int ws_ok,
                                                    size_t z) {
    const int tid = (int)threadIdx.x;
    float4 acc = make_float4(0.f, 0.f, 0.f, 0.f);
    for (int pass = 0; pass < 6; ++pass) {
        const float4* fp = (const float4*)(f + pass * z);
        float4 v[8];
#pragma unroll
        for (int i = 0; i < 8; ++i)
            v[i] = fp[(size_t)blockIdx.x * 2048 + i * 256 + tid];
#pragma unroll
        for (int i = 0; i < 8; ++i) {
            acc.x += v[i].x; acc.y += v[i].y; acc.z += v[i].z; acc.w += v[i].w;
        }
    }
    float s = acc.x + acc.y + acc.z + acc.w;
    asm volatile("" :: "v"(s));              // keep loads live (rule #17)
#pragma unroll
    for (int d = 1; d < 64; d <<= 1) s += __shfl_xor(s, d, 64);
    if (ws_ok && (tid & 63) == 0)
        ws[(size_t)blockIdx.x * 4 + (tid >> 6)] = s;
}

// --------------------------------------------- probe 2: center+south pattern
// R4's exact row-pair read pattern (2 float4/ch: rows h, h+1), 3 passes.
__global__ __launch_bounds__(256) void probe_2row(const float* f,
                                                  float* ws, int ws_ok,
                                                  size_t z) {
    const int cpx = gridDim.x >> 3;
    const int bid = ((int)blockIdx.x & 7) * cpx + ((int)blockIdx.x >> 3);
    const int wband = bid & 3;
    const int hband = (bid >> 2) & 31;
    const int b = bid >> 7;

    const int g = (int)threadIdx.x & 31;
    const int r = (int)threadIdx.x >> 5;
    const int w0 = (wband << 7) + (g << 2);
    const int h = (hband << 3) + r;
    const bool vS = (h + 1) < AF_H;

    float4 acc = make_float4(0.f, 0.f, 0.f, 0.f);
    for (int pass = 0; pass < 3; ++pass) {
        const float* pc = f + pass * z + (size_t)b * AF_C * AF_PLANE
                        + (size_t)h * AF_W + w0;
        const float* ps = pc + (vS ? AF_W : 0);
#pragma unroll
        for (int c = 0; c < AF_C; ++c) {
            const float4 cc = *(const float4*)pc;
            const float4 cs = *(const float4*)ps;
            pc += AF_PLANE; ps += AF_PLANE;
            acc.x += cc.x + cs.x; acc.y += cc.y + cs.y;
            acc.z += cc.z + cs.z; acc.w += cc.w + cs.w;
        }
    }
    float s = acc.x + acc.y + acc.z + acc.w;
    asm volatile("" :: "v"(s));              // keep loads live
#pragma unroll
    for (int d = 1; d < 64; d <<= 1) s += __shfl_xor(s, d, 64);
    if (ws_ok && ((int)threadIdx.x & 63) == 0)
        ws[32768 / 4 + (size_t)blockIdx.x * 4 + ((int)threadIdx.x >> 6)] = s;
}

extern "C" void kernel_launch(void* const* d_in, const int* in_sizes, int n_in,
                              void* d_out, int out_size, void* d_ws, size_t ws_size,
                              hipStream_t stream) {
    const float* f = (const float*)d_in[0];
    float* out = (float*)d_out;
    float* ws = (float*)d_ws;
    const int ws_ok = (ws_size >= (size_t)40960) ? 1 : 0;
    const size_t z = 0;   // runtime zero: defeats cross-pass load CSE

    affinity_diag_main<<<512, 256, 0, stream>>>(f, out, z);
    probe_stream<<<2048, 256, 0, stream>>>(f, ws, ws_ok, z);
    probe_2row<<<512, 256, 0, stream>>>(f, ws, ws_ok, z);
}

// Round 12
// 24.892 us; speedup vs baseline: 4.1847x; 4.1847x over previous
//
#include <hip/hip_runtime.h>

// AffinityFeature, symmetric formulation. R12: PAGE-LOCAL mapping.
// Identical instruction stream to R2 (best: 24.9us); ONLY the thread->pixel
// mapping changes: block = 2 rows x 512 cols = exactly one aligned 4KB page
// of each channel plane (rows 2j,2j+1). All 4 waves of the block touch the
// SAME 1-2 pages per channel iteration (vs 8-16 before) -> UTCL1-resident.
// Theory: the invariant ~1000cy/channel-iteration across R2/R4/R8/R10 is
// address-translation thrash from the 512KB plane stride.

#define AF_B 4
#define AF_C 32
#define AF_H 256
#define AF_W 512
#define AF_EPS 1e-12f
#define AF_PLANE ((size_t)AF_H * AF_W)

__global__ __launch_bounds__(256) void affinity_page_kernel(const float* __restrict__ f,
                                                            float* __restrict__ out) {
    // XCD-aware swizzle: 512 blocks -> 64-block contiguous slab per XCD
    // (= 128 consecutive rows of one batch; south-row sharing stays in-XCD).
    const int cpx = gridDim.x >> 3;
    const int bid = ((int)blockIdx.x & 7) * cpx + ((int)blockIdx.x >> 3);

    const int rp = bid & 127;            // row-pair index 0..127
    const int b = bid >> 7;              // batch
    const int h0 = rp << 1;

    const int g = (int)threadIdx.x & 127;   // col group (4 px each)
    const int r = (int)threadIdx.x >> 7;    // row in pair: 0 or 1
    const int w0 = g << 2;                  // 0..508
    const int h = h0 + r;

    const bool vS = (h + 1) < AF_H;   // south row exists
    const bool vR = (w0 + 4) < AF_W;  // col w0+4 exists
    const bool vL = w0 > 0;           // col w0-1 exists
    const float mS = vS ? 1.0f : 0.0f;
    const float mR = vR ? 1.0f : 0.0f;
    const float mRS = mR * mS;
    const float mLS = (vL ? 1.0f : 0.0f) * mS;
    const int offR = vR ? 4 : 0;
    const int offL = vL ? -1 : 0;

    const float* pc = f + (size_t)b * AF_C * AF_PLANE + (size_t)h * AF_W + w0;
    const float* ps = pc + (vS ? AF_W : 0);

    float ssq0=0,ssq1=0,ssq2=0,ssq3=0, ssqR=0;          // center row |v|^2
    float nsq0=0,nsq1=0,nsq2=0,nsq3=0, nsqL=0,nsqR=0;   // south row |v|^2
    float dE0=0,dE1=0,dE2=0,dE3=0;
    float dS0=0,dS1=0,dS2=0,dS3=0;
    float dSE0=0,dSE1=0,dSE2=0,dSE3=0;
    float dSW0=0,dSW1=0,dSW2=0,dSW3=0;

#pragma unroll
    for (int c = 0; c < AF_C; ++c) {
        const float4 cc = *(const float4*)pc;
        const float ccR = pc[offR] * mR;
        float4 cs = *(const float4*)ps;
        const float csR = ps[offR] * mRS;
        const float csL = ps[offL] * mLS;
        cs.x *= mS; cs.y *= mS; cs.z *= mS; cs.w *= mS;
        pc += AF_PLANE; ps += AF_PLANE;

        ssq0 += cc.x*cc.x; ssq1 += cc.y*cc.y; ssq2 += cc.z*cc.z; ssq3 += cc.w*cc.w;
        ssqR += ccR*ccR;
        nsq0 += cs.x*cs.x; nsq1 += cs.y*cs.y; nsq2 += cs.z*cs.z; nsq3 += cs.w*cs.w;
        nsqL += csL*csL;   nsqR += csR*csR;
        dE0 += cc.x*cc.y;  dE1 += cc.y*cc.z;  dE2 += cc.z*cc.w;  dE3 += cc.w*ccR;
        dS0 += cc.x*cs.x;  dS1 += cc.y*cs.y;  dS2 += cc.z*cs.z;  dS3 += cc.w*cs.w;
        dSE0 += cc.x*cs.y; dSE1 += cc.y*cs.z; dSE2 += cc.z*cs.w; dSE3 += cc.w*csR;
        dSW0 += cc.x*csL;  dSW1 += cc.y*cs.x; dSW2 += cc.z*cs.y; dSW3 += cc.w*cs.z;
    }

    const float ic0 = 1.0f / fmaxf(sqrtf(ssq0), AF_EPS);
    const float ic1 = 1.0f / fmaxf(sqrtf(ssq1), AF_EPS);
    const float ic2 = 1.0f / fmaxf(sqrtf(ssq2), AF_EPS);
    const float ic3 = 1.0f / fmaxf(sqrtf(ssq3), AF_EPS);
    const float icR = 1.0f / fmaxf(sqrtf(ssqR), AF_EPS);
    const float is0 = 1.0f / fmaxf(sqrtf(nsq0), AF_EPS);
    const float is1 = 1.0f / fmaxf(sqrtf(nsq1), AF_EPS);
    const float is2 = 1.0f / fmaxf(sqrtf(nsq2), AF_EPS);
    const float is3 = 1.0f / fmaxf(sqrtf(nsq3), AF_EPS);
    const float isL = 1.0f / fmaxf(sqrtf(nsqL), AF_EPS);
    const float isR = 1.0f / fmaxf(sqrtf(nsqR), AF_EPS);

    const float E0 = fmaxf(dE0*ic0*ic1, 0.0f);
    const float E1 = fmaxf(dE1*ic1*ic2, 0.0f);
    const float E2 = fmaxf(dE2*ic2*ic3, 0.0f);
    const float E3 = fmaxf(dE3*ic3*icR, 0.0f);
    const float S0 = fmaxf(dS0*ic0*is0, 0.0f);
    const float S1 = fmaxf(dS1*ic1*is1, 0.0f);
    const float S2 = fmaxf(dS2*ic2*is2, 0.0f);
    const float S3 = fmaxf(dS3*ic3*is3, 0.0f);
    const float SE0 = fmaxf(dSE0*ic0*is1, 0.0f);
    const float SE1 = fmaxf(dSE1*ic1*is2, 0.0f);
    const float SE2 = fmaxf(dSE2*ic2*is3, 0.0f);
    const float SE3 = fmaxf(dSE3*ic3*isR, 0.0f);
    const float SW0 = fmaxf(dSW0*ic0*isL, 0.0f);
    const float SW1 = fmaxf(dSW1*ic1*is0, 0.0f);
    const float SW2 = fmaxf(dSW2*ic2*is1, 0.0f);
    const float SW3 = fmaxf(dSW3*ic3*is2, 0.0f);

    float* ob = out + (size_t)b * 8 * AF_PLANE + (size_t)h * AF_W + w0;

    // forward channels at (h, w0..w0+3), aligned float4
    *(float4*)(ob + 4*AF_PLANE) = make_float4(E0,E1,E2,E3);
    *(float4*)(ob + 6*AF_PLANE) = make_float4(S0,S1,S2,S3);
    *(float4*)(ob + 7*AF_PLANE) = make_float4(SE0,SE1,SE2,SE3);
    *(float4*)(ob + 5*AF_PLANE) = make_float4(SW0,SW1,SW2,SW3);

    // a=3 (W) at (h, w0+1..w0+4)
    float* o3 = ob + 3*AF_PLANE;
    o3[1] = E0; o3[2] = E1; o3[3] = E2;
    if (vR) o3[4] = E3;
    if (!vL) o3[0] = 0.0f;      // W of (h,0) OOB

    if (vS) {
        float* on = ob + AF_W;  // row h+1, col w0
        // a=1 (N) at (h+1, w0..w0+3)
        *(float4*)(on + 1*AF_PLANE) = make_float4(S0,S1,S2,S3);
        // a=0 (NW) at (h+1, w0+1..w0+4)
        float* o0 = on;
        o0[1] = SE0; o0[2] = SE1; o0[3] = SE2;
        if (vR) o0[4] = SE3;
        if (!vL) o0[0] = 0.0f;  // NW of (h+1,0) OOB
        // a=2 (NE) at (h+1, w0-1..w0+2)
        float* o2 = on + 2*AF_PLANE;
        if (vL) o2[-1] = SW0;
        o2[0] = SW1; o2[1] = SW2; o2[2] = SW3;
        if (!vR) o2[3] = 0.0f;  // NE of (h+1, W-1) OOB
    }

    if (h == 0) {               // N/NW/NE rows at h=0 are all OOB -> zero
        float* oz = out + (size_t)b * 8 * AF_PLANE + w0;
        const float4 z4 = make_float4(0.0f, 0.0f, 0.0f, 0.0f);
        *(float4*)(oz + 0*AF_PLANE) = z4;
        *(float4*)(oz + 1*AF_PLANE) = z4;
        *(float4*)(oz + 2*AF_PLANE) = z4;
    }
}

extern "C" void kernel_launch(void* const* d_in, const int* in_sizes, int n_in,
                              void* d_out, int out_size, void* d_ws, size_t ws_size,
                              hipStream_t stream) {
    const float* f = (const float*)d_in[0];
    float* out = (float*)d_out;
    // grid = 4 batches x 128 row-pairs = 512 blocks; block = 2 rows x 512 cols
    affinity_page_kernel<<<512, 256, 0, stream>>>(f, out);
}